// Round 1
// baseline (180.741 us; speedup 1.0000x reference)
//
#include <hip/hip_runtime.h>

#define CCH 32
#define BCH 6
#define HH  180
#define WW  320
#define NN  (HH*WW)          // 57600
#define BATCH 32
#define TI  6                 // ceil(180/32)
#define TJ  10                // 320/32

__global__ __launch_bounds__(256) void fused_flatten_deflatten(
    const float* __restrict__ latent,    // (B, C, N)
    const float* __restrict__ w_flat,    // (BCH, C)
    const float* __restrict__ b_flat,    // (BCH,)
    const float* __restrict__ w_deflat,  // (C, BCH)
    const float* __restrict__ b_deflat,  // (C,)
    const float* __restrict__ se,        // (1, C, N)
    const int*   __restrict__ unwalk,    // (N,)
    float* __restrict__ recon,           // (B, C, N)
    float* __restrict__ flat_out)        // (B, BCH, N)
{
    __shared__ float s_wf[BCH*CCH];   // [o][c]
    __shared__ float s_wd[CCH*BCH];   // [c][o]
    __shared__ float s_bf[BCH];
    __shared__ float s_bd[CCH];

    const int t = threadIdx.x;
    if (t < BCH*CCH) { s_wf[t] = w_flat[t]; s_wd[t] = w_deflat[t]; }
    if (t < BCH)     s_bf[t] = b_flat[t];
    if (t < CCH)     s_bd[t] = b_deflat[t];
    __syncthreads();

    const int bx = blockIdx.x;
    const int b  = bx / (TI*TJ);
    const int r  = bx % (TI*TJ);
    const int i0 = (r / TJ) * 32;
    const int j0 = (r % TJ) * 32;

    const int ti = t >> 3;            // 0..31
    const int tj = (t & 7) << 2;      // 0,4,...,28
    const int i  = i0 + ti;
    if (i >= HH) return;              // bottom partial strip
    const int p  = i * WW + j0 + tj;  // 16B-aligned (p % 4 == 0)

    const float* latb   = latent + (size_t)b * (CCH*NN) + p;
    float*       reconb = recon  + (size_t)b * (CCH*NN) + p;

    const int4 n4 = *reinterpret_cast<const int4*>(unwalk + p);

    // ---- pass 1: flat = W_f @ latent + b_f (raster domain, coalesced reads)
    float acc[BCH][4];
    #pragma unroll
    for (int o = 0; o < BCH; ++o) {
        const float bo = s_bf[o];
        acc[o][0] = bo; acc[o][1] = bo; acc[o][2] = bo; acc[o][3] = bo;
    }

    #pragma unroll 8
    for (int c = 0; c < CCH; ++c) {
        const float4 x = *reinterpret_cast<const float4*>(latb + (size_t)c * NN);
        #pragma unroll
        for (int o = 0; o < BCH; ++o) {
            const float w = s_wf[o*CCH + c];
            acc[o][0] += w * x.x;
            acc[o][1] += w * x.y;
            acc[o][2] += w * x.z;
            acc[o][3] += w * x.w;
        }
    }

    // ---- scatter flat to walk domain (contiguous n-range per z-aligned tile)
    float* fb = flat_out + (size_t)b * (BCH*NN);
    #pragma unroll
    for (int o = 0; o < BCH; ++o) {
        float* fo = fb + (size_t)o * NN;
        fo[n4.x] = acc[o][0];
        fo[n4.y] = acc[o][1];
        fo[n4.z] = acc[o][2];
        fo[n4.w] = acc[o][3];
    }

    // ---- pass 2: recon = W_d @ flat + b_d + se[:, n] (coalesced writes)
    #pragma unroll 8
    for (int c = 0; c < CCH; ++c) {
        const float* sec = se + (size_t)c * NN;
        float y0 = s_bd[c] + sec[n4.x];
        float y1 = s_bd[c] + sec[n4.y];
        float y2 = s_bd[c] + sec[n4.z];
        float y3 = s_bd[c] + sec[n4.w];
        #pragma unroll
        for (int o = 0; o < BCH; ++o) {
            const float w = s_wd[c*BCH + o];
            y0 += w * acc[o][0];
            y1 += w * acc[o][1];
            y2 += w * acc[o][2];
            y3 += w * acc[o][3];
        }
        *reinterpret_cast<float4*>(reconb + (size_t)c * NN) =
            make_float4(y0, y1, y2, y3);
    }
}

extern "C" void kernel_launch(void* const* d_in, const int* in_sizes, int n_in,
                              void* d_out, int out_size, void* d_ws, size_t ws_size,
                              hipStream_t stream) {
    const float* latent   = (const float*)d_in[0];
    const float* w_flat   = (const float*)d_in[1];
    const float* b_flat   = (const float*)d_in[2];
    const float* w_deflat = (const float*)d_in[3];
    const float* b_deflat = (const float*)d_in[4];
    const float* se       = (const float*)d_in[5];
    const int*   unwalk   = (const int*)d_in[7];   // d_in[6] = walk_idx (unused)

    float* recon = (float*)d_out;
    float* flat  = (float*)d_out + (size_t)BATCH * CCH * NN;

    dim3 grid(BATCH * TI * TJ);   // 32 * 60 = 1920 blocks
    dim3 block(256);
    fused_flatten_deflatten<<<grid, block, 0, stream>>>(
        latent, w_flat, b_flat, w_deflat, b_deflat, se, unwalk, recon, flat);
}

// Round 2
// 157.657 us; speedup vs baseline: 1.1464x; 1.1464x over previous
//
#include <hip/hip_runtime.h>

#define CCH 32
#define BCH 6
#define HH  180
#define WW  320
#define NN  (HH*WW)          // 57600
#define BATCH 32
#define TI  6                 // i0 = 0,32,...,160 (160 is partial: 20 rows)
#define TJ  5                 // j0 = 0,64,...,256
#define TILES (TI*TJ)         // 30

// Each block: one 32x64 z-aligned tile, 256 threads in Morton order.
// Thread t owns a 2x4 raster block = two 2x2 quads = walk ranks [n_q, n_q+8).
__global__ __launch_bounds__(256) void fused_flatten_deflatten(
    const float* __restrict__ latent,    // (B, C, N)
    const float* __restrict__ w_flat,    // (BCH, C)
    const float* __restrict__ b_flat,    // (BCH,)
    const float* __restrict__ w_deflat,  // (C, BCH)
    const float* __restrict__ b_deflat,  // (C,)
    const float* __restrict__ se,        // (1, C, N)
    const int*   __restrict__ unwalk,    // (N,)
    float* __restrict__ recon,           // (B, C, N)
    float* __restrict__ flat_out)        // (B, BCH, N)
{
    __shared__ float s_wf[BCH*CCH];   // [o][c]
    __shared__ float s_wd[CCH*BCH];   // [c][o]
    __shared__ float s_bf[BCH];
    __shared__ float s_bd[CCH];
    __shared__ int   s_nbase;

    const int t  = threadIdx.x;
    const int bx = blockIdx.x;
    const int b  = bx / TILES;
    const int r  = bx % TILES;
    const int i0 = (r / TJ) * 32;
    const int j0 = (r % TJ) * 64;

    if (t < BCH*CCH) { s_wf[t] = w_flat[t]; s_wd[t] = w_deflat[t]; }
    if (t < BCH)     s_bf[t] = b_flat[t];
    if (t < CCH)     s_bd[t] = b_deflat[t];
    if (t == 0)      s_nbase = unwalk[i0*WW + j0];
    __syncthreads();

    // Morton decode: t bits (lsb->msb) = i1,j2,i2,j3,i3,j4,i4,j5
    const int li = (((t>>0)&1)<<1) | (((t>>2)&1)<<2) | (((t>>4)&1)<<3) | (((t>>6)&1)<<4);
    const int lj = (((t>>1)&1)<<2) | (((t>>3)&1)<<3) | (((t>>5)&1)<<4) | (((t>>7)&1)<<5);
    const int i  = i0 + li;           // row-pair base (even)
    const int j  = j0 + lj;           // col base (mult of 4)
    if (i + 1 >= HH) return;          // bottom partial strip: rows >= 180

    const bool full = (i0 <= 128);    // full 32x64 tile -> walk range contiguous
    const int n_q = full ? (s_nbase + 8*t) : unwalk[i*WW + j];
    // quad rank base is always 0 mod 4 -> float4-aligned; second quad at n_q+4

    const float* latb   = latent + (size_t)b * (CCH*NN) + i*WW + j;
    float*       reconb = recon  + (size_t)b * (CCH*NN) + i*WW + j;

    // ---- pass 1: flat = W_f @ latent + b_f  (acc[o][k], k = di*4+dj)
    float acc[BCH][8];
    #pragma unroll
    for (int o = 0; o < BCH; ++o) {
        const float bo = s_bf[o];
        #pragma unroll
        for (int k = 0; k < 8; ++k) acc[o][k] = bo;
    }

    #pragma unroll 8
    for (int c = 0; c < CCH; ++c) {
        const float4 xt = *reinterpret_cast<const float4*>(latb + (size_t)c*NN);
        const float4 xb = *reinterpret_cast<const float4*>(latb + (size_t)c*NN + WW);
        #pragma unroll
        for (int o = 0; o < BCH; ++o) {
            const float w = s_wf[o*CCH + c];
            acc[o][0] += w*xt.x; acc[o][1] += w*xt.y; acc[o][2] += w*xt.z; acc[o][3] += w*xt.w;
            acc[o][4] += w*xb.x; acc[o][5] += w*xb.y; acc[o][6] += w*xb.z; acc[o][7] += w*xb.w;
        }
    }

    // ---- flat store: z-order mapping z0..z7 = k0,k1,k4,k5,k2,k3,k6,k7
    float* fb = flat_out + (size_t)b * (BCH*NN) + n_q;
    #pragma unroll
    for (int o = 0; o < BCH; ++o) {
        float* fo = fb + (size_t)o * NN;
        *reinterpret_cast<float4*>(fo)     = make_float4(acc[o][0], acc[o][1], acc[o][4], acc[o][5]);
        *reinterpret_cast<float4*>(fo + 4) = make_float4(acc[o][2], acc[o][3], acc[o][6], acc[o][7]);
    }

    // ---- pass 2: recon = W_d @ flat + b_d + se (se read in walk domain, coalesced)
    #pragma unroll 8
    for (int c = 0; c < CCH; ++c) {
        const float* sec = se + (size_t)c*NN + n_q;
        const float4 sa = *reinterpret_cast<const float4*>(sec);      // z0..z3
        const float4 sb = *reinterpret_cast<const float4*>(sec + 4);  // z4..z7
        const float bd = s_bd[c];
        float y0 = bd + sa.x, y1 = bd + sa.y, y2 = bd + sb.x, y3 = bd + sb.y; // top row
        float y4 = bd + sa.z, y5 = bd + sa.w, y6 = bd + sb.z, y7 = bd + sb.w; // bottom row
        #pragma unroll
        for (int o = 0; o < BCH; ++o) {
            const float w = s_wd[c*BCH + o];
            y0 += w*acc[o][0]; y1 += w*acc[o][1]; y2 += w*acc[o][2]; y3 += w*acc[o][3];
            y4 += w*acc[o][4]; y5 += w*acc[o][5]; y6 += w*acc[o][6]; y7 += w*acc[o][7];
        }
        *reinterpret_cast<float4*>(reconb + (size_t)c*NN)      = make_float4(y0,y1,y2,y3);
        *reinterpret_cast<float4*>(reconb + (size_t)c*NN + WW) = make_float4(y4,y5,y6,y7);
    }
}

extern "C" void kernel_launch(void* const* d_in, const int* in_sizes, int n_in,
                              void* d_out, int out_size, void* d_ws, size_t ws_size,
                              hipStream_t stream) {
    const float* latent   = (const float*)d_in[0];
    const float* w_flat   = (const float*)d_in[1];
    const float* b_flat   = (const float*)d_in[2];
    const float* w_deflat = (const float*)d_in[3];
    const float* b_deflat = (const float*)d_in[4];
    const float* se       = (const float*)d_in[5];
    const int*   unwalk   = (const int*)d_in[7];   // d_in[6] = walk_idx (unused)

    float* recon = (float*)d_out;
    float* flat  = (float*)d_out + (size_t)BATCH * CCH * NN;

    dim3 grid(BATCH * TILES);   // 32 * 30 = 960 blocks
    dim3 block(256);
    fused_flatten_deflatten<<<grid, block, 0, stream>>>(
        latent, w_flat, b_flat, w_deflat, b_deflat, se, unwalk, recon, flat);
}